// Round 1
// baseline (738.663 us; speedup 1.0000x reference)
//
#include <hip/hip_runtime.h>

// Problem constants
#define HW   4096
#define CCH  64     // concat channels
#define DQ   32     // q/k dim
#define OC   32     // output channels
#define NBATCH 8

// Workspace layout (float offsets)
#define WSV_OFF 0u                      // 32*64
#define Q_OFF   2048u                   // 8*4096*32
#define K_OFF   (Q_OFF + 1048576u)      // 8*4096*32
#define V2_OFF  (K_OFF + 1048576u)      // 8*32*4096  [b][o][m]
#define XS_OFF  (V2_OFF + 1048576u)     // 8*32*4096  [b][o][n]
#define ZP_OFF  (XS_OFF + 1048576u)     // 4*8*4096 partial sums
#define ZS_OFF  (ZP_OFF + 131072u)      // 8*4096 column scales = gamma/Z
// total = ZS_OFF + 32768 = 4360192 floats (~17.4 MB)

// ---------------------------------------------------------------------------
// Kernel 0: Wsv[o][ci] = sum_c Wsc[o][c] * Wv[c][ci]
__global__ __launch_bounds__(256) void k_wcomb(const float* __restrict__ Wsc,
                                               const float* __restrict__ Wv,
                                               float* __restrict__ Wsv) {
    int t = blockIdx.x * 256 + threadIdx.x;
    if (t < OC * CCH) {
        int o = t / CCH, ci = t % CCH;
        float s = 0.f;
        #pragma unroll
        for (int c = 0; c < CCH; ++c) s += Wsc[o * CCH + c] * Wv[c * CCH + ci];
        Wsv[t] = s;
    }
}

// ---------------------------------------------------------------------------
// Kernel 1: per-pixel projections.
// q[b][n][d], k[b][n][d] (row-major rows of 32), v2[b][o][m], xs[b][o][n]
__global__ __launch_bounds__(256) void k_proj(
    const float* __restrict__ x1, const float* __restrict__ x2,
    const float* __restrict__ Wq, const float* __restrict__ bq,
    const float* __restrict__ Wk, const float* __restrict__ bk,
    const float* __restrict__ Wsv, const float* __restrict__ Wsc,
    float* __restrict__ q, float* __restrict__ k,
    float* __restrict__ v2, float* __restrict__ xs) {
    __shared__ float wq[DQ * CCH], wk[DQ * CCH], wsv[OC * CCH], wsc[OC * CCH];
    __shared__ float bqs[DQ], bks[DQ];
    int t = threadIdx.x;
    for (int i = t; i < DQ * CCH; i += 256) {
        wq[i] = Wq[i]; wk[i] = Wk[i]; wsv[i] = Wsv[i]; wsc[i] = Wsc[i];
    }
    if (t < DQ) { bqs[t] = bq[t]; bks[t] = bk[t]; }
    __syncthreads();

    int p = blockIdx.x * 256 + t;
    int b = p >> 12, n = p & 4095;
    const float* x1b = x1 + (size_t)b * 32 * HW;
    const float* x2b = x2 + (size_t)b * 32 * HW;
    float x[CCH];
    #pragma unroll
    for (int c = 0; c < 32; ++c) x[c] = x1b[c * HW + n];
    #pragma unroll
    for (int c = 0; c < 32; ++c) x[32 + c] = x2b[c * HW + n];

    size_t rowqk = ((size_t)b * HW + n) * DQ;
    for (int d0 = 0; d0 < DQ; d0 += 4) {
        float4 qv, kv;
        float* qp = &qv.x; float* kp = &kv.x;
        #pragma unroll
        for (int i = 0; i < 4; ++i) {
            int d = d0 + i;
            float aq = bqs[d], ak = bks[d];
            const float* wqr = wq + d * CCH;
            const float* wkr = wk + d * CCH;
            #pragma unroll
            for (int c = 0; c < CCH; ++c) { aq += wqr[c] * x[c]; ak += wkr[c] * x[c]; }
            qp[i] = aq; kp[i] = ak;
        }
        *(float4*)(q + rowqk + d0) = qv;
        *(float4*)(k + rowqk + d0) = kv;
    }
    for (int o = 0; o < OC; ++o) {
        float av = 0.f, ax = 0.f;
        const float* wvr = wsv + o * CCH;
        const float* wsr = wsc + o * CCH;
        #pragma unroll
        for (int c = 0; c < CCH; ++c) { av += wvr[c] * x[c]; ax += wsr[c] * x[c]; }
        v2[((size_t)b * OC + o) * HW + n] = av;
        xs[((size_t)b * OC + o) * HW + n] = ax;
    }
}

// ---------------------------------------------------------------------------
// Kernel 2: partial column sums Zp[nc][b][m] = sum_{n in chunk nc} exp(q[n].k[m])
// grid = 8 b * 16 coltiles * 4 nchunks = 512 blocks, 256 threads (1 col each)
__global__ __launch_bounds__(256) void k_stats(const float* __restrict__ q,
                                               const float* __restrict__ k,
                                               float* __restrict__ Zp) {
    int bid = blockIdx.x;
    int nc = bid & 3;
    int ct = (bid >> 2) & 15;
    int b  = bid >> 6;
    int t = threadIdx.x;
    int col = ct * 256 + t;

    const float* krow = k + ((size_t)b * HW + col) * DQ;
    float4 k0 = ((const float4*)krow)[0];
    float4 k1 = ((const float4*)krow)[1];
    float4 k2 = ((const float4*)krow)[2];
    float4 k3 = ((const float4*)krow)[3];
    float4 k4 = ((const float4*)krow)[4];
    float4 k5 = ((const float4*)krow)[5];
    float4 k6 = ((const float4*)krow)[6];
    float4 k7 = ((const float4*)krow)[7];

    __shared__ float qs[64 * DQ];
    float z = 0.f;
    int n0 = nc * 1024;
    for (int np = 0; np < 1024; np += 64) {
        const float4* qsrc = (const float4*)(q + ((size_t)b * HW + n0 + np) * DQ);
        ((float4*)qs)[t * 2]     = qsrc[t * 2];
        ((float4*)qs)[t * 2 + 1] = qsrc[t * 2 + 1];
        __syncthreads();
        #pragma unroll 4
        for (int i = 0; i < 64; ++i) {
            const float* qr = qs + i * DQ;
            float4 b0 = ((const float4*)qr)[0];
            float4 b1 = ((const float4*)qr)[1];
            float4 b2 = ((const float4*)qr)[2];
            float4 b3 = ((const float4*)qr)[3];
            float4 b4 = ((const float4*)qr)[4];
            float4 b5 = ((const float4*)qr)[5];
            float4 b6 = ((const float4*)qr)[6];
            float4 b7 = ((const float4*)qr)[7];
            float s = k0.x*b0.x + k0.y*b0.y + k0.z*b0.z + k0.w*b0.w
                    + k1.x*b1.x + k1.y*b1.y + k1.z*b1.z + k1.w*b1.w
                    + k2.x*b2.x + k2.y*b2.y + k2.z*b2.z + k2.w*b2.w
                    + k3.x*b3.x + k3.y*b3.y + k3.z*b3.z + k3.w*b3.w
                    + k4.x*b4.x + k4.y*b4.y + k4.z*b4.z + k4.w*b4.w
                    + k5.x*b5.x + k5.y*b5.y + k5.z*b5.z + k5.w*b5.w
                    + k6.x*b6.x + k6.y*b6.y + k6.z*b6.z + k6.w*b6.w
                    + k7.x*b7.x + k7.y*b7.y + k7.z*b7.z + k7.w*b7.w;
            z += __expf(s);
        }
        __syncthreads();
    }
    Zp[(size_t)nc * (NBATCH * HW) + (size_t)b * HW + col] = z;
}

// ---------------------------------------------------------------------------
// Kernel 3: column scale ZS[i] = gamma / sum_nc Zp[nc][i]
__global__ __launch_bounds__(256) void k_scale(const float* __restrict__ Zp,
                                               const float* __restrict__ gamma,
                                               float* __restrict__ ZS) {
    int i = blockIdx.x * 256 + threadIdx.x;
    if (i < NBATCH * HW) {
        float s = Zp[i] + Zp[32768 + i] + Zp[65536 + i] + Zp[98304 + i];
        ZS[i] = gamma[0] / s;
    }
}

// ---------------------------------------------------------------------------
// Kernel 4: out[b][o][n] = sum_m (v2[o][m]*ZS[m]) * exp(q[n].k[m]) + xs[o][n]
// grid = 8 b * 64 ntiles = 512 blocks, 256 threads. n-tile = 64 n, all 32 o.
__global__ __launch_bounds__(256) void k_attn(
    const float* __restrict__ q, const float* __restrict__ k,
    const float* __restrict__ v2, const float* __restrict__ xs,
    const float* __restrict__ ZS, float* __restrict__ out) {
    __shared__ float kT[64 * DQ];   // k rows for this m-tile
    __shared__ float vv[OC * 64];   // scaled v2, [o][mm]
    __shared__ float pT[64 * 64];   // exp(s), [mm][nn]

    int t = threadIdx.x;
    int bid = blockIdx.x;
    int nt = bid & 63;
    int b = bid >> 6;
    int n0 = nt * 64;
    int tn = t & 63, wv = t >> 6;      // phase-1 identity
    int to = t >> 5, tn2 = t & 31;     // phase-2 identity: 4 o's x 2 n's

    // own q row in registers (persistent)
    const float4* qr = (const float4*)(q + ((size_t)b * HW + n0 + tn) * DQ);
    float4 q0 = qr[0], q1 = qr[1], q2 = qr[2], q3 = qr[3];
    float4 q4 = qr[4], q5 = qr[5], q6 = qr[6], q7 = qr[7];

    float acc[4][2] = {{0.f, 0.f}, {0.f, 0.f}, {0.f, 0.f}, {0.f, 0.f}};

    for (int m0 = 0; m0 < HW; m0 += 64) {
        // stage k tile (2048 floats, 2 float4/thread)
        const float4* ksrc = (const float4*)(k + ((size_t)b * HW + m0) * DQ);
        ((float4*)kT)[t * 2]     = ksrc[t * 2];
        ((float4*)kT)[t * 2 + 1] = ksrc[t * 2 + 1];
        // stage scaled v2 tile: thread handles 8 consecutive mm of one o
        {
            int o  = t >> 3;
            int mm = (t & 7) * 8;
            const float* vsrc = v2 + ((size_t)b * OC + o) * HW + m0 + mm;
            const float* zsrc = ZS + (size_t)b * HW + m0 + mm;
            float4 va = ((const float4*)vsrc)[0], vb = ((const float4*)vsrc)[1];
            float4 za = ((const float4*)zsrc)[0], zb = ((const float4*)zsrc)[1];
            float* vvp = vv + o * 64 + mm;
            vvp[0] = va.x * za.x; vvp[1] = va.y * za.y;
            vvp[2] = va.z * za.z; vvp[3] = va.w * za.w;
            vvp[4] = vb.x * zb.x; vvp[5] = vb.y * zb.y;
            vvp[6] = vb.z * zb.z; vvp[7] = vb.w * zb.w;
        }
        __syncthreads();

        // phase 1: p[mm][tn] = exp(q[tn] . k[mm]) for this wave's 16 mm
        #pragma unroll
        for (int j = 0; j < 16; ++j) {
            int mm = wv * 16 + j;
            const float* kr = kT + mm * DQ;
            float4 a0 = ((const float4*)kr)[0];
            float4 a1 = ((const float4*)kr)[1];
            float4 a2 = ((const float4*)kr)[2];
            float4 a3 = ((const float4*)kr)[3];
            float4 a4 = ((const float4*)kr)[4];
            float4 a5 = ((const float4*)kr)[5];
            float4 a6 = ((const float4*)kr)[6];
            float4 a7 = ((const float4*)kr)[7];
            float s = q0.x*a0.x + q0.y*a0.y + q0.z*a0.z + q0.w*a0.w
                    + q1.x*a1.x + q1.y*a1.y + q1.z*a1.z + q1.w*a1.w
                    + q2.x*a2.x + q2.y*a2.y + q2.z*a2.z + q2.w*a2.w
                    + q3.x*a3.x + q3.y*a3.y + q3.z*a3.z + q3.w*a3.w
                    + q4.x*a4.x + q4.y*a4.y + q4.z*a4.z + q4.w*a4.w
                    + q5.x*a5.x + q5.y*a5.y + q5.z*a5.z + q5.w*a5.w
                    + q6.x*a6.x + q6.y*a6.y + q6.z*a6.z + q6.w*a6.w
                    + q7.x*a7.x + q7.y*a7.y + q7.z*a7.z + q7.w*a7.w;
            pT[mm * 64 + tn] = __expf(s);
        }
        __syncthreads();

        // phase 2: rank-64 update of acc[4 o][2 n]
        #pragma unroll 8
        for (int mm = 0; mm < 64; mm += 2) {
            float2 pa = *(const float2*)(pT + mm * 64 + 2 * tn2);
            float2 pb = *(const float2*)(pT + (mm + 1) * 64 + 2 * tn2);
            #pragma unroll
            for (int i = 0; i < 4; ++i) {
                float2 w = *(const float2*)(vv + (to * 4 + i) * 64 + mm);
                acc[i][0] += w.x * pa.x + w.y * pb.x;
                acc[i][1] += w.x * pa.y + w.y * pb.y;
            }
        }
        __syncthreads();
    }

    // epilogue: add xs, write out
    #pragma unroll
    for (int i = 0; i < 4; ++i) {
        int o = to * 4 + i;
        size_t base = ((size_t)b * OC + o) * HW + n0 + 2 * tn2;
        float2 xv = *(const float2*)(xs + base);
        float2 r;
        r.x = acc[i][0] + xv.x;
        r.y = acc[i][1] + xv.y;
        *(float2*)(out + base) = r;
    }
}

// ---------------------------------------------------------------------------
extern "C" void kernel_launch(void* const* d_in, const int* in_sizes, int n_in,
                              void* d_out, int out_size, void* d_ws, size_t ws_size,
                              hipStream_t stream) {
    const float* x1    = (const float*)d_in[0];
    const float* x2    = (const float*)d_in[1];
    const float* Wq    = (const float*)d_in[2];
    const float* bq    = (const float*)d_in[3];
    const float* Wk    = (const float*)d_in[4];
    const float* bk    = (const float*)d_in[5];
    const float* Wv    = (const float*)d_in[6];
    const float* Wsc   = (const float*)d_in[7];
    const float* gamma = (const float*)d_in[8];
    float* out = (float*)d_out;
    float* ws  = (float*)d_ws;

    float* wsv = ws + WSV_OFF;
    float* q   = ws + Q_OFF;
    float* k   = ws + K_OFF;
    float* v2  = ws + V2_OFF;
    float* xs  = ws + XS_OFF;
    float* zp  = ws + ZP_OFF;
    float* zs  = ws + ZS_OFF;

    k_wcomb<<<8, 256, 0, stream>>>(Wsc, Wv, wsv);
    k_proj<<<128, 256, 0, stream>>>(x1, x2, Wq, bq, Wk, bk, wsv, Wsc,
                                    q, k, v2, xs);
    k_stats<<<512, 256, 0, stream>>>(q, k, zp);
    k_scale<<<128, 256, 0, stream>>>(zp, gamma, zs);
    k_attn<<<512, 256, 0, stream>>>(q, k, v2, xs, zs, out);
}

// Round 2
// 264.077 us; speedup vs baseline: 2.7972x; 2.7972x over previous
//
#include <hip/hip_runtime.h>

typedef __attribute__((ext_vector_type(8))) __bf16 bf16x8;
typedef __attribute__((ext_vector_type(4))) float f32x4;
typedef unsigned int uint32;
typedef unsigned short ushort16;

#define HW   4096
#define CCH  64
#define DQ   32
#define OC   32

// Workspace layout (float offsets)
#define WSV_OFF 0u                       // 32*64 f32
#define QB_OFF  2048u                    // bf16 [b][n][32]  -> 524288 floats
#define KB_OFF  (QB_OFF + 524288u)       // bf16 [b][m][32]
#define V2_OFF  (KB_OFF + 524288u)       // f32  [b][o][m]
#define XS_OFF  (V2_OFF + 1048576u)      // f32  [b][o][n]
#define ZS_OFF  (XS_OFF + 1048576u)      // f32  gamma/Z [b][m]
#define VZB_OFF (ZS_OFF + 32768u)        // bf16 [b][o][m] -> 524288 floats
// total ~3.7M floats (~14.8 MB)

__device__ __forceinline__ uint32 f2bf(float x) {
    uint32 u = __builtin_bit_cast(uint32, x);
    return (u + 0x7fffu + ((u >> 16) & 1u)) >> 16;
}
__device__ __forceinline__ uint32 packbf(float a, float b) {
    return f2bf(a) | (f2bf(b) << 16);
}
__device__ __forceinline__ bf16x8 ldfrag(const ushort16* p) {
    union { uint4 u; bf16x8 f; } t;
    t.u = *(const uint4*)p;
    return t.f;
}

// ---------------------------------------------------------------------------
// Kernel 0: Wsv = Wsc @ Wv
__global__ __launch_bounds__(256) void k_wcomb(const float* __restrict__ Wsc,
                                               const float* __restrict__ Wv,
                                               float* __restrict__ Wsv) {
    int t = blockIdx.x * 256 + threadIdx.x;
    if (t < OC * CCH) {
        int o = t / CCH, ci = t % CCH;
        float s = 0.f;
        #pragma unroll
        for (int c = 0; c < CCH; ++c) s += Wsc[o * CCH + c] * Wv[c * CCH + ci];
        Wsv[t] = s;
    }
}

// ---------------------------------------------------------------------------
// Kernel 1: projections. qb/kb bf16 rows of 32; v2/xs fp32 [b][o][pixel]
__global__ __launch_bounds__(256) void k_proj(
    const float* __restrict__ x1, const float* __restrict__ x2,
    const float* __restrict__ Wq, const float* __restrict__ bq,
    const float* __restrict__ Wk, const float* __restrict__ bk,
    const float* __restrict__ Wsv, const float* __restrict__ Wsc,
    ushort16* __restrict__ qb, ushort16* __restrict__ kb,
    float* __restrict__ v2, float* __restrict__ xs) {
    __shared__ float wq[DQ * CCH], wk[DQ * CCH], wsv[OC * CCH], wsc[OC * CCH];
    __shared__ float bqs[DQ], bks[DQ];
    int t = threadIdx.x;
    for (int i = t; i < DQ * CCH; i += 256) {
        wq[i] = Wq[i]; wk[i] = Wk[i]; wsv[i] = Wsv[i]; wsc[i] = Wsc[i];
    }
    if (t < DQ) { bqs[t] = bq[t]; bks[t] = bk[t]; }
    __syncthreads();

    int p = blockIdx.x * 256 + t;
    int b = p >> 12, n = p & 4095;
    const float* x1b = x1 + (size_t)b * 32 * HW;
    const float* x2b = x2 + (size_t)b * 32 * HW;
    float x[CCH];
    #pragma unroll
    for (int c = 0; c < 32; ++c) x[c] = x1b[c * HW + n];
    #pragma unroll
    for (int c = 0; c < 32; ++c) x[32 + c] = x2b[c * HW + n];

    size_t rowqk = ((size_t)b * HW + n) * DQ;   // ushort elems
    for (int d0 = 0; d0 < DQ; d0 += 8) {
        float qv[8], kv[8];
        #pragma unroll
        for (int i = 0; i < 8; ++i) {
            int d = d0 + i;
            float aq = bqs[d], ak = bks[d];
            const float* wqr = wq + d * CCH;
            const float* wkr = wk + d * CCH;
            #pragma unroll
            for (int c = 0; c < CCH; ++c) { aq += wqr[c] * x[c]; ak += wkr[c] * x[c]; }
            qv[i] = aq; kv[i] = ak;
        }
        uint4 uq, uk;
        uq.x = packbf(qv[0], qv[1]); uq.y = packbf(qv[2], qv[3]);
        uq.z = packbf(qv[4], qv[5]); uq.w = packbf(qv[6], qv[7]);
        uk.x = packbf(kv[0], kv[1]); uk.y = packbf(kv[2], kv[3]);
        uk.z = packbf(kv[4], kv[5]); uk.w = packbf(kv[6], kv[7]);
        *(uint4*)(qb + rowqk + d0) = uq;
        *(uint4*)(kb + rowqk + d0) = uk;
    }
    for (int o = 0; o < OC; ++o) {
        float av = 0.f, ax = 0.f;
        const float* wvr = wsv + o * CCH;
        const float* wsr = wsc + o * CCH;
        #pragma unroll
        for (int c = 0; c < CCH; ++c) { av += wvr[c] * x[c]; ax += wsr[c] * x[c]; }
        v2[((size_t)b * OC + o) * HW + n] = av;
        xs[((size_t)b * OC + o) * HW + n] = ax;
    }
}

// ---------------------------------------------------------------------------
// Kernel 2: zs[b][m] = gamma / sum_n exp(q_n . k_m)   (MFMA, k-frag persistent)
// grid = 8 b * 64 = 512 blocks; wave handles one 16-m tile, sweeps all n.
__global__ __launch_bounds__(256) void k_stats(const ushort16* __restrict__ kb,
                                               const ushort16* __restrict__ qb,
                                               const float* __restrict__ gamma,
                                               float* __restrict__ zs) {
    int t = threadIdx.x;
    int w = t >> 6, l = t & 63;
    int lr = l & 15, lq = l >> 4;
    int bid = blockIdx.x;
    int b = bid >> 6, blk = bid & 63;
    int m0 = (blk * 4 + w) * 16;

    const ushort16* kbb = kb + ((size_t)b * HW) * DQ;
    const ushort16* qp  = qb + ((size_t)b * HW) * DQ + lr * DQ + lq * 8;
    bf16x8 af = ldfrag(kbb + (size_t)(m0 + lr) * DQ + lq * 8);

    f32x4 acc = {0.f, 0.f, 0.f, 0.f};
    #pragma unroll 2
    for (int n0 = 0; n0 < HW; n0 += 16) {
        bf16x8 bfg = ldfrag(qp);
        qp += 16 * DQ;
        f32x4 z = {0.f, 0.f, 0.f, 0.f};
        f32x4 s = __builtin_amdgcn_mfma_f32_16x16x32_bf16(af, bfg, z, 0, 0, 0);
        acc.x += __expf(s.x); acc.y += __expf(s.y);
        acc.z += __expf(s.z); acc.w += __expf(s.w);
    }
    #pragma unroll
    for (int off = 1; off < 16; off <<= 1) {
        acc.x += __shfl_xor(acc.x, off);
        acc.y += __shfl_xor(acc.y, off);
        acc.z += __shfl_xor(acc.z, off);
        acc.w += __shfl_xor(acc.w, off);
    }
    if (lr == 0) {
        float g = gamma[0];
        size_t base = (size_t)b * HW + m0 + lq * 4;
        zs[base + 0] = g / acc.x;
        zs[base + 1] = g / acc.y;
        zs[base + 2] = g / acc.z;
        zs[base + 3] = g / acc.w;
    }
}

// ---------------------------------------------------------------------------
// Kernel 3: vzb[b][o][m] = bf16(v2 * zs[b][m])
__global__ __launch_bounds__(256) void k_vz(const float* __restrict__ v2,
                                            const float* __restrict__ zs,
                                            ushort16* __restrict__ vzb) {
    int t = blockIdx.x * 256 + threadIdx.x;   // 262144 threads
    int e0 = t * 4;
    int b = e0 >> 17;                          // 32*4096 elems per batch
    int m = e0 & (HW - 1);
    float4 v = *(const float4*)(v2 + e0);
    float4 z = *(const float4*)(zs + (size_t)b * HW + m);
    uint2 r;
    r.x = packbf(v.x * z.x, v.y * z.y);
    r.y = packbf(v.z * z.z, v.w * z.w);
    *(uint2*)(vzb + e0) = r;
}

// ---------------------------------------------------------------------------
// Kernel 4: out[b][o][n] = sum_m vzb[o][m] * exp(q_n . k_m) + xs[o][n]
// grid = 8 b * 64 = 512 blocks; wave owns a 16-n tile, sweeps m.
// P repack C-layout -> B-operand via per-wave 1KB LDS frag buffer (no barrier).
__global__ __launch_bounds__(256) void k_attn(
    const ushort16* __restrict__ qb, const ushort16* __restrict__ kb,
    const ushort16* __restrict__ vzb, const float* __restrict__ xs,
    float* __restrict__ out) {
    __shared__ ushort16 fb[4096];   // 4 waves * 2 phases * 512
    int t = threadIdx.x;
    int w = t >> 6, l = t & 63;
    int lr = l & 15, lq = l >> 4;
    int bid = blockIdx.x;
    int b = bid >> 6, nt = bid & 63;
    int n0 = nt * 64 + w * 16;

    ushort16* fbw = fb + w * 1024;
    // fragment-order write slot: lane's 4 exp values for S-subtile 0 land here
    int aw = (lr + ((lq >> 1) << 4)) * 8 + (lq & 1) * 4;

    bf16x8 qf = ldfrag(qb + ((size_t)b * HW + n0 + lr) * DQ + lq * 8);
    const ushort16* kp = kb + ((size_t)b * HW + lr) * DQ + lq * 8;
    const ushort16* vp = vzb + ((size_t)b * OC + lr) * HW + lq * 8;

    f32x4 acc0 = {0.f, 0.f, 0.f, 0.f};
    f32x4 acc1 = {0.f, 0.f, 0.f, 0.f};

    for (int m0 = 0; m0 < HW; m0 += 64) {
        #pragma unroll
        for (int ph = 0; ph < 2; ++ph) {
            int mb = m0 + ph * 32;
            ushort16* fbr = fbw + ph * 512;
            bf16x8 a0  = ldfrag(kp + (size_t)mb * DQ);
            bf16x8 a1  = ldfrag(kp + (size_t)(mb + 16) * DQ);
            bf16x8 va0 = ldfrag(vp + mb);
            bf16x8 va1 = ldfrag(vp + 16 * HW + mb);
            f32x4 zz = {0.f, 0.f, 0.f, 0.f};
            f32x4 s0 = __builtin_amdgcn_mfma_f32_16x16x32_bf16(a0, qf, zz, 0, 0, 0);
            f32x4 s1 = __builtin_amdgcn_mfma_f32_16x16x32_bf16(a1, qf, zz, 0, 0, 0);
            uint2 p0, p1;
            p0.x = packbf(__expf(s0.x), __expf(s0.y));
            p0.y = packbf(__expf(s0.z), __expf(s0.w));
            p1.x = packbf(__expf(s1.x), __expf(s1.y));
            p1.y = packbf(__expf(s1.z), __expf(s1.w));
            *(uint2*)(fbr + aw)       = p0;   // m-local 0..15  -> lane quads 0,1
            *(uint2*)(fbr + aw + 256) = p1;   // m-local 16..31 -> lane quads 2,3
            bf16x8 pf = ldfrag(fbr + l * 8);  // B2 frag: P[n=lr][m=lq*8+j]
            acc0 = __builtin_amdgcn_mfma_f32_16x16x32_bf16(va0, pf, acc0, 0, 0, 0);
            acc1 = __builtin_amdgcn_mfma_f32_16x16x32_bf16(va1, pf, acc1, 0, 0, 0);
        }
    }

    // epilogue: C layout col=lane&15=n, row=quad*4+reg=o
    int n = n0 + lr;
    #pragma unroll
    for (int r = 0; r < 4; ++r) {
        int o0 = lq * 4 + r;
        size_t i0 = ((size_t)b * OC + o0) * HW + n;
        size_t i1 = ((size_t)b * OC + o0 + 16) * HW + n;
        out[i0] = acc0[r] + xs[i0];
        out[i1] = acc1[r] + xs[i1];
    }
}

// ---------------------------------------------------------------------------
extern "C" void kernel_launch(void* const* d_in, const int* in_sizes, int n_in,
                              void* d_out, int out_size, void* d_ws, size_t ws_size,
                              hipStream_t stream) {
    const float* x1    = (const float*)d_in[0];
    const float* x2    = (const float*)d_in[1];
    const float* Wq    = (const float*)d_in[2];
    const float* bq    = (const float*)d_in[3];
    const float* Wk    = (const float*)d_in[4];
    const float* bk    = (const float*)d_in[5];
    const float* Wv    = (const float*)d_in[6];
    const float* Wsc   = (const float*)d_in[7];
    const float* gamma = (const float*)d_in[8];
    float* out = (float*)d_out;
    float* ws  = (float*)d_ws;

    float*    wsv = ws + WSV_OFF;
    ushort16* qbp = (ushort16*)(ws + QB_OFF);
    ushort16* kbp = (ushort16*)(ws + KB_OFF);
    float*    v2  = ws + V2_OFF;
    float*    xsp = ws + XS_OFF;
    float*    zsp = ws + ZS_OFF;
    ushort16* vzb = (ushort16*)(ws + VZB_OFF);

    k_wcomb<<<8, 256, 0, stream>>>(Wsc, Wv, wsv);
    k_proj<<<128, 256, 0, stream>>>(x1, x2, Wq, bq, Wk, bk, wsv, Wsc,
                                    qbp, kbp, v2, xsp);
    k_stats<<<512, 256, 0, stream>>>(kbp, qbp, gamma, zsp);
    k_vz<<<1024, 256, 0, stream>>>(v2, zsp, vzb);
    k_attn<<<512, 256, 0, stream>>>(qbp, kbp, vzb, xsp, out);
}

// Round 3
// 179.188 us; speedup vs baseline: 4.1223x; 1.4737x over previous
//
#include <hip/hip_runtime.h>

typedef __attribute__((ext_vector_type(8))) __bf16 bf16x8;
typedef __attribute__((ext_vector_type(4))) float f32x4;
typedef unsigned int uint32;

#define HW   4096
#define CCH  64
#define DQ   32
#define OC   32
#define LOG2E 1.4426950408889634f

// Workspace layout (float offsets)
#define WSV_OFF  0u                       // 32*64 f32
#define QB_OFF   2048u                    // bf16 [b][n][32] (pre-scaled by log2e)
#define KB_OFF   (QB_OFF + 524288u)       // bf16 [b][m][32]
#define V2_OFF   (KB_OFF + 524288u)       // f32  [b][o][m]
#define XS_OFF   (V2_OFF + 1048576u)      // f32  [b][o][n]
#define ZP_OFF   (XS_OFF + 1048576u)      // f32  [4][b][m] partial Z
#define ZS_OFF   (ZP_OFF + 131072u)       // f32  gamma/Z [b][m]
#define VZB_OFF  (ZS_OFF + 32768u)        // bf16 [b][o][m]
#define OUTP_OFF (VZB_OFF + 524288u)      // f32  [4][b][o][n] partial out
// total = OUTP_OFF + 4194304 = 8030208 floats (~32.1 MB)

__device__ __forceinline__ uint32 f2bf(float x) {
    uint32 u = __builtin_bit_cast(uint32, x);
    return (u + 0x7fffu + ((u >> 16) & 1u)) >> 16;
}
__device__ __forceinline__ uint32 packbf(float a, float b) {
    return f2bf(a) | (f2bf(b) << 16);
}
__device__ __forceinline__ bf16x8 ldfrag(const unsigned short* p) {
    union { uint4 u; bf16x8 f; } t;
    t.u = *(const uint4*)p;
    return t.f;
}
__device__ __forceinline__ float fexp2(float x) {
#if __has_builtin(__builtin_amdgcn_exp2f)
    return __builtin_amdgcn_exp2f(x);
#else
    return __expf(x * 0.6931471805599453f);
#endif
}

// ---------------------------------------------------------------------------
// Kernel 0: Wsv = Wsc @ Wv
__global__ __launch_bounds__(256) void k_wcomb(const float* __restrict__ Wsc,
                                               const float* __restrict__ Wv,
                                               float* __restrict__ Wsv) {
    int t = blockIdx.x * 256 + threadIdx.x;
    if (t < OC * CCH) {
        int o = t / CCH, ci = t % CCH;
        float s = 0.f;
        #pragma unroll
        for (int c = 0; c < CCH; ++c) s += Wsc[o * CCH + c] * Wv[c * CCH + ci];
        Wsv[t] = s;
    }
}

// ---------------------------------------------------------------------------
// Kernel 1: projections, 4-way output split (wave g: 0=q,1=k,2=v2,3=xs).
// 512 blocks x 256 thr; block = 64 pixels; each wave computes its 32 outputs.
__global__ __launch_bounds__(256) void k_proj(
    const float* __restrict__ x1, const float* __restrict__ x2,
    const float* __restrict__ Wq, const float* __restrict__ bq,
    const float* __restrict__ Wk, const float* __restrict__ bk,
    const float* __restrict__ Wsv, const float* __restrict__ Wsc,
    unsigned short* __restrict__ qb, unsigned short* __restrict__ kb,
    float* __restrict__ v2, float* __restrict__ xs) {
    __shared__ float wall[4 * DQ * CCH];
    __shared__ float bqs[DQ], bks[DQ];
    int t = threadIdx.x;
    for (int i = t; i < 4 * DQ * CCH; i += 256) {
        float v;
        if (i < 2048)      v = Wq[i];
        else if (i < 4096) v = Wk[i - 2048];
        else if (i < 6144) v = Wsv[i - 4096];
        else               v = Wsc[i - 6144];
        wall[i] = v;
    }
    if (t < DQ) { bqs[t] = bq[t]; bks[t] = bk[t]; }
    __syncthreads();

    int g = t >> 6, l = t & 63;
    int p = blockIdx.x * 64 + l;
    int b = p >> 12, n = p & 4095;
    const float* x1b = x1 + (size_t)b * 32 * HW;
    const float* x2b = x2 + (size_t)b * 32 * HW;
    float x[CCH];
    #pragma unroll
    for (int c = 0; c < 32; ++c) x[c] = x1b[c * HW + n];
    #pragma unroll
    for (int c = 0; c < 32; ++c) x[32 + c] = x2b[c * HW + n];

    const float* W = wall + g * (DQ * CCH);

    if (g < 2) {
        // q (g=0, add bias, scale by log2e) / k (g=1, add bias)
        unsigned short* dst = (g == 0) ? qb : kb;
        const float* bias = (g == 0) ? bqs : bks;
        float scale = (g == 0) ? LOG2E : 1.0f;
        size_t row = ((size_t)b * HW + n) * DQ;
        for (int d0 = 0; d0 < DQ; d0 += 8) {
            float r[8];
            #pragma unroll
            for (int i = 0; i < 8; ++i) {
                int d = d0 + i;
                float a = bias[d];
                const float* wr = W + d * CCH;
                #pragma unroll
                for (int c = 0; c < CCH; ++c) a += wr[c] * x[c];
                r[i] = a * scale;
            }
            uint4 u;
            u.x = packbf(r[0], r[1]); u.y = packbf(r[2], r[3]);
            u.z = packbf(r[4], r[5]); u.w = packbf(r[6], r[7]);
            *(uint4*)(dst + row + d0) = u;
        }
    } else {
        // v2 (g=2) / xs (g=3), fp32 column-major [b][o][pixel]
        float* dst = (g == 2) ? v2 : xs;
        for (int o = 0; o < OC; ++o) {
            float a = 0.f;
            const float* wr = W + o * CCH;
            #pragma unroll
            for (int c = 0; c < CCH; ++c) a += wr[c] * x[c];
            dst[((size_t)b * OC + o) * HW + n] = a;
        }
    }
}

// ---------------------------------------------------------------------------
// Kernel 2: partial Zp[nc][b][m] = sum_{n in chunk} exp2(q_n . k_m)
// grid = 8 b * 32 mg * 4 nc = 1024 blocks; wave = 2 m-frags (32 m), 1024 n.
__global__ __launch_bounds__(256, 4) void k_stats(
    const unsigned short* __restrict__ kb, const unsigned short* __restrict__ qb,
    float* __restrict__ zp) {
    int t = threadIdx.x;
    int w = t >> 6, l = t & 63;
    int lr = l & 15, lq = l >> 4;
    int bid = blockIdx.x;
    int nc = bid & 3, mg = (bid >> 2) & 31, b = bid >> 7;
    int m0 = mg * 128 + w * 32;

    const unsigned short* kbb = kb + ((size_t)b * HW) * DQ;
    bf16x8 af0 = ldfrag(kbb + (size_t)(m0 + lr) * DQ + lq * 8);
    bf16x8 af1 = ldfrag(kbb + (size_t)(m0 + 16 + lr) * DQ + lq * 8);
    const unsigned short* qp = qb + ((size_t)b * HW + nc * 1024 + lr) * DQ + lq * 8;

    f32x4 acc0 = {0.f, 0.f, 0.f, 0.f};
    f32x4 acc1 = {0.f, 0.f, 0.f, 0.f};
    f32x4 zz = {0.f, 0.f, 0.f, 0.f};
    #pragma unroll 4
    for (int i = 0; i < 64; ++i) {
        bf16x8 qf = ldfrag(qp);
        qp += 16 * DQ;
        f32x4 s0 = __builtin_amdgcn_mfma_f32_16x16x32_bf16(af0, qf, zz, 0, 0, 0);
        f32x4 s1 = __builtin_amdgcn_mfma_f32_16x16x32_bf16(af1, qf, zz, 0, 0, 0);
        acc0.x += fexp2(s0.x); acc0.y += fexp2(s0.y);
        acc0.z += fexp2(s0.z); acc0.w += fexp2(s0.w);
        acc1.x += fexp2(s1.x); acc1.y += fexp2(s1.y);
        acc1.z += fexp2(s1.z); acc1.w += fexp2(s1.w);
    }
    #pragma unroll
    for (int off = 1; off < 16; off <<= 1) {
        acc0.x += __shfl_xor(acc0.x, off); acc0.y += __shfl_xor(acc0.y, off);
        acc0.z += __shfl_xor(acc0.z, off); acc0.w += __shfl_xor(acc0.w, off);
        acc1.x += __shfl_xor(acc1.x, off); acc1.y += __shfl_xor(acc1.y, off);
        acc1.z += __shfl_xor(acc1.z, off); acc1.w += __shfl_xor(acc1.w, off);
    }
    if (lr == 0) {
        size_t base = (size_t)nc * 32768 + (size_t)b * HW;
        zp[base + m0 + lq * 4 + 0] = acc0.x;
        zp[base + m0 + lq * 4 + 1] = acc0.y;
        zp[base + m0 + lq * 4 + 2] = acc0.z;
        zp[base + m0 + lq * 4 + 3] = acc0.w;
        zp[base + m0 + 16 + lq * 4 + 0] = acc1.x;
        zp[base + m0 + 16 + lq * 4 + 1] = acc1.y;
        zp[base + m0 + 16 + lq * 4 + 2] = acc1.z;
        zp[base + m0 + 16 + lq * 4 + 3] = acc1.w;
    }
}

// ---------------------------------------------------------------------------
// Kernel 3: ZS = gamma / sum_nc Zp
__global__ __launch_bounds__(256) void k_scale(const float* __restrict__ zp,
                                               const float* __restrict__ gamma,
                                               float* __restrict__ zs) {
    int i = (blockIdx.x * 256 + threadIdx.x) * 4;
    float4 a = *(const float4*)(zp + i);
    float4 b = *(const float4*)(zp + 32768 + i);
    float4 c = *(const float4*)(zp + 65536 + i);
    float4 d = *(const float4*)(zp + 98304 + i);
    float g = gamma[0];
    float4 r;
    r.x = g / (a.x + b.x + c.x + d.x);
    r.y = g / (a.y + b.y + c.y + d.y);
    r.z = g / (a.z + b.z + c.z + d.z);
    r.w = g / (a.w + b.w + c.w + d.w);
    *(float4*)(zs + i) = r;
}

// ---------------------------------------------------------------------------
// Kernel 4: vzb[b][o][m] = bf16(v2 * zs[b][m])
__global__ __launch_bounds__(256) void k_vz(const float* __restrict__ v2,
                                            const float* __restrict__ zs,
                                            unsigned short* __restrict__ vzb) {
    int t = blockIdx.x * 256 + threadIdx.x;
    int e0 = t * 4;
    int b = e0 >> 17;
    int m = e0 & (HW - 1);
    float4 v = *(const float4*)(v2 + e0);
    float4 z = *(const float4*)(zs + (size_t)b * HW + m);
    uint2 r;
    r.x = packbf(v.x * z.x, v.y * z.y);
    r.y = packbf(v.z * z.z, v.w * z.w);
    *(uint2*)(vzb + e0) = r;
}

// ---------------------------------------------------------------------------
// Kernel 5: partial outp[mc][b][o][n] = sum_{m in chunk} vzb[o][m]*exp2(q_n.k_m)
// grid = 8 b * 32 ng * 4 mc = 1024 blocks; wave = 2 n-tiles (32 n), 1024 m.
__global__ __launch_bounds__(256, 4) void k_attn(
    const unsigned short* __restrict__ qb, const unsigned short* __restrict__ kb,
    const unsigned short* __restrict__ vzb, float* __restrict__ outp) {
    __shared__ unsigned short fb[8192];   // 4 waves * 2 tiles * 2 phases * 512
    int t = threadIdx.x;
    int w = t >> 6, l = t & 63;
    int lr = l & 15, lq = l >> 4;
    int bid = blockIdx.x;
    int mc = bid & 3, ng = (bid >> 2) & 31, b = bid >> 7;
    int nA = ng * 128 + w * 32;

    unsigned short* fbw = fb + w * 2048;
    int aw = (lr + ((lq >> 1) << 4)) * 8 + (lq & 1) * 4;

    bf16x8 qfA = ldfrag(qb + ((size_t)b * HW + nA + lr) * DQ + lq * 8);
    bf16x8 qfB = ldfrag(qb + ((size_t)b * HW + nA + 16 + lr) * DQ + lq * 8);
    const unsigned short* kp = kb + ((size_t)b * HW + lr) * DQ + lq * 8;
    const unsigned short* vp = vzb + ((size_t)b * OC + lr) * HW + lq * 8;

    f32x4 accA0 = {0.f,0.f,0.f,0.f}, accA1 = {0.f,0.f,0.f,0.f};
    f32x4 accB0 = {0.f,0.f,0.f,0.f}, accB1 = {0.f,0.f,0.f,0.f};
    f32x4 zz = {0.f,0.f,0.f,0.f};

    int mbeg = mc * 1024;
    for (int m0 = mbeg; m0 < mbeg + 1024; m0 += 64) {
        #pragma unroll
        for (int ph = 0; ph < 2; ++ph) {
            int mb = m0 + ph * 32;
            unsigned short* fA = fbw + ph * 512;
            unsigned short* fB = fbw + 1024 + ph * 512;
            bf16x8 a0  = ldfrag(kp + (size_t)mb * DQ);
            bf16x8 a1  = ldfrag(kp + (size_t)(mb + 16) * DQ);
            bf16x8 va0 = ldfrag(vp + mb);
            bf16x8 va1 = ldfrag(vp + 16 * HW + mb);
            f32x4 sA0 = __builtin_amdgcn_mfma_f32_16x16x32_bf16(a0, qfA, zz, 0, 0, 0);
            f32x4 sA1 = __builtin_amdgcn_mfma_f32_16x16x32_bf16(a1, qfA, zz, 0, 0, 0);
            f32x4 sB0 = __builtin_amdgcn_mfma_f32_16x16x32_bf16(a0, qfB, zz, 0, 0, 0);
            f32x4 sB1 = __builtin_amdgcn_mfma_f32_16x16x32_bf16(a1, qfB, zz, 0, 0, 0);
            uint2 pA0, pA1, pB0, pB1;
            pA0.x = packbf(fexp2(sA0.x), fexp2(sA0.y));
            pA0.y = packbf(fexp2(sA0.z), fexp2(sA0.w));
            pA1.x = packbf(fexp2(sA1.x), fexp2(sA1.y));
            pA1.y = packbf(fexp2(sA1.z), fexp2(sA1.w));
            pB0.x = packbf(fexp2(sB0.x), fexp2(sB0.y));
            pB0.y = packbf(fexp2(sB0.z), fexp2(sB0.w));
            pB1.x = packbf(fexp2(sB1.x), fexp2(sB1.y));
            pB1.y = packbf(fexp2(sB1.z), fexp2(sB1.w));
            *(uint2*)(fA + aw)       = pA0;
            *(uint2*)(fA + aw + 256) = pA1;
            *(uint2*)(fB + aw)       = pB0;
            *(uint2*)(fB + aw + 256) = pB1;
            bf16x8 pfA = ldfrag(fA + l * 8);
            bf16x8 pfB = ldfrag(fB + l * 8);
            accA0 = __builtin_amdgcn_mfma_f32_16x16x32_bf16(va0, pfA, accA0, 0, 0, 0);
            accA1 = __builtin_amdgcn_mfma_f32_16x16x32_bf16(va1, pfA, accA1, 0, 0, 0);
            accB0 = __builtin_amdgcn_mfma_f32_16x16x32_bf16(va0, pfB, accB0, 0, 0, 0);
            accB1 = __builtin_amdgcn_mfma_f32_16x16x32_bf16(va1, pfB, accB1, 0, 0, 0);
        }
    }

    // partial write (no xs): C layout col=lane&15=n, row=lq*4+r=o
    int n_A = nA + lr, n_B = nA + 16 + lr;
    size_t obase = ((size_t)mc * 8 + b) * OC * HW;
    #pragma unroll
    for (int r = 0; r < 4; ++r) {
        int o0 = lq * 4 + r;
        outp[obase + (size_t)o0 * HW + n_A]        = accA0[r];
        outp[obase + (size_t)(o0 + 16) * HW + n_A] = accA1[r];
        outp[obase + (size_t)o0 * HW + n_B]        = accB0[r];
        outp[obase + (size_t)(o0 + 16) * HW + n_B] = accB1[r];
    }
}

// ---------------------------------------------------------------------------
// Kernel 6: out = sum_mc outp[mc] + xs
__global__ __launch_bounds__(256) void k_red(const float* __restrict__ outp,
                                             const float* __restrict__ xs,
                                             float* __restrict__ out) {
    int i = (blockIdx.x * 256 + threadIdx.x) * 4;
    float4 a = *(const float4*)(outp + i);
    float4 b = *(const float4*)(outp + 1048576 + i);
    float4 c = *(const float4*)(outp + 2097152 + i);
    float4 d = *(const float4*)(outp + 3145728 + i);
    float4 x = *(const float4*)(xs + i);
    float4 r;
    r.x = a.x + b.x + c.x + d.x + x.x;
    r.y = a.y + b.y + c.y + d.y + x.y;
    r.z = a.z + b.z + c.z + d.z + x.z;
    r.w = a.w + b.w + c.w + d.w + x.w;
    *(float4*)(out + i) = r;
}

// ---------------------------------------------------------------------------
extern "C" void kernel_launch(void* const* d_in, const int* in_sizes, int n_in,
                              void* d_out, int out_size, void* d_ws, size_t ws_size,
                              hipStream_t stream) {
    const float* x1    = (const float*)d_in[0];
    const float* x2    = (const float*)d_in[1];
    const float* Wq    = (const float*)d_in[2];
    const float* bq    = (const float*)d_in[3];
    const float* Wk    = (const float*)d_in[4];
    const float* bk    = (const float*)d_in[5];
    const float* Wv    = (const float*)d_in[6];
    const float* Wsc   = (const float*)d_in[7];
    const float* gamma = (const float*)d_in[8];
    float* out = (float*)d_out;
    float* ws  = (float*)d_ws;

    float*          wsv  = ws + WSV_OFF;
    unsigned short* qbp  = (unsigned short*)(ws + QB_OFF);
    unsigned short* kbp  = (unsigned short*)(ws + KB_OFF);
    float*          v2   = ws + V2_OFF;
    float*          xsp  = ws + XS_OFF;
    float*          zpp  = ws + ZP_OFF;
    float*          zsp  = ws + ZS_OFF;
    unsigned short* vzb  = (unsigned short*)(ws + VZB_OFF);
    float*          outp = ws + OUTP_OFF;

    k_wcomb<<<8, 256, 0, stream>>>(Wsc, Wv, wsv);
    k_proj<<<512, 256, 0, stream>>>(x1, x2, Wq, bq, Wk, bk, wsv, Wsc,
                                    qbp, kbp, v2, xsp);
    k_stats<<<1024, 256, 0, stream>>>(kbp, qbp, zpp);
    k_scale<<<32, 256, 0, stream>>>(zpp, gamma, zsp);
    k_vz<<<1024, 256, 0, stream>>>(v2, zsp, vzb);
    k_attn<<<1024, 256, 0, stream>>>(qbp, kbp, vzb, outp);
    k_red<<<1024, 256, 0, stream>>>(outp, xsp, out);
}